// Round 1
// baseline (2065.205 us; speedup 1.0000x reference)
//
#include <hip/hip_runtime.h>
#include <hip/hip_bf16.h>
#include <stdint.h>
#include <stddef.h>

#define T_TOK 2048
#define HDIM  2048
#define IDIM  1024
#define NEXP  32
#define TOPK  6
#define CAP   768
#define RSCALE 1.5f
#define SWLIMIT 10.0f

typedef __attribute__((ext_vector_type(8))) short bf16x8;
typedef __attribute__((ext_vector_type(4))) float f32x4;

__device__ __forceinline__ unsigned short f2b(float f) {
  union { float f; unsigned u; } v; v.f = f;
  unsigned r = v.u + 0x7FFF + ((v.u >> 16) & 1);   // RNE
  return (unsigned short)(r >> 16);
}
__device__ __forceinline__ float b2f(unsigned short h) {
  union { unsigned u; float f; } v; v.u = ((unsigned)h) << 16; return v.f;
}

// ---------------- zero counts ----------------
__global__ void zero32_kernel(int* c) {
  if (threadIdx.x < NEXP) c[threadIdx.x] = 0;
}

// ---------------- x fp32 -> bf16 ----------------
__global__ void cvt_x_kernel(const float* __restrict__ x, unsigned short* __restrict__ xb) {
  int i = (blockIdx.x * 256 + threadIdx.x) * 4;
  float4 f = *(const float4*)(x + i);
  ushort4 o;
  o.x = f2b(f.x); o.y = f2b(f.y); o.z = f2b(f.z); o.w = f2b(f.w);
  *(ushort4*)(xb + i) = o;
}

// ---------------- router: scores + top-6 + dispatch ----------------
__global__ void router_kernel(const float* __restrict__ x, const float* __restrict__ gw,
                              const float* __restrict__ bias, int* __restrict__ counts,
                              int* __restrict__ tok_list, float* __restrict__ w_list) {
  const int wv = threadIdx.x >> 6;
  const int lane = threadIdx.x & 63;
  const int t = blockIdx.x * 4 + wv;
  const float* hp = x + (size_t)t * HDIM;

  float h[32];
#pragma unroll
  for (int j = 0; j < 32; ++j) h[j] = hp[j * 64 + lane];

  float sc[NEXP], sb[NEXP];
#pragma unroll
  for (int e = 0; e < NEXP; ++e) {
    const float* g = gw + (size_t)e * HDIM;
    float a = 0.f;
#pragma unroll
    for (int j = 0; j < 32; ++j) a += h[j] * g[j * 64 + lane];
#pragma unroll
    for (int s = 32; s; s >>= 1) a += __shfl_xor(a, s);
    // sqrt(softplus(a))
    float sp = (a > 20.f) ? a : log1pf(expf(a));
    float s1 = sqrtf(sp);
    sc[e] = s1;
    sb[e] = s1 + bias[e];
  }

  unsigned mask = 0;
  int idxs[TOPK]; float ws[TOPK];
  float sum = 0.f;
#pragma unroll
  for (int r = 0; r < TOPK; ++r) {
    float best = -1e30f; int bi = 0; float bu = 0.f;
#pragma unroll
    for (int e = 0; e < NEXP; ++e) {
      bool take = (!(mask & (1u << e))) && (sb[e] > best);
      if (take) { best = sb[e]; bi = e; bu = sc[e]; }
    }
    mask |= (1u << bi);
    idxs[r] = bi; ws[r] = bu; sum += bu;
  }

  if (lane == 0) {
    float inv = RSCALE / sum;
#pragma unroll
    for (int r = 0; r < TOPK; ++r) {
      int e = idxs[r];
      int slot = atomicAdd(&counts[e], 1);
      if (slot < CAP) {
        tok_list[e * CAP + slot] = t;
        w_list[e * CAP + slot] = ws[r] * inv;
      }
    }
  }
}

// ---------------- silu(g)*u elementwise (optional clamp), bf16 in/out ----------------
__global__ void silu_mul_kernel(const unsigned short* __restrict__ G,
                                const unsigned short* __restrict__ U,
                                unsigned short* __restrict__ O,
                                int do_clamp, long n4) {
  long i = (long)blockIdx.x * 256 + threadIdx.x;
  if (i >= n4) return;
  ushort4 g4 = *(const ushort4*)(G + i * 4);
  ushort4 u4 = *(const ushort4*)(U + i * 4);
  ushort4 o;
  float g, u, s;
  g = b2f(g4.x); u = b2f(u4.x); s = g / (1.f + expf(-g)) * u;
  if (do_clamp) s = fminf(fmaxf(s, -SWLIMIT), SWLIMIT);
  o.x = f2b(s);
  g = b2f(g4.y); u = b2f(u4.y); s = g / (1.f + expf(-g)) * u;
  if (do_clamp) s = fminf(fmaxf(s, -SWLIMIT), SWLIMIT);
  o.y = f2b(s);
  g = b2f(g4.z); u = b2f(u4.z); s = g / (1.f + expf(-g)) * u;
  if (do_clamp) s = fminf(fmaxf(s, -SWLIMIT), SWLIMIT);
  o.z = f2b(s);
  g = b2f(g4.w); u = b2f(u4.w); s = g / (1.f + expf(-g)) * u;
  if (do_clamp) s = fminf(fmaxf(s, -SWLIMIT), SWLIMIT);
  o.w = f2b(s);
  *(ushort4*)(O + i * 4) = o;
}

// ---------------- generic bt-GEMM: C[M,N] = A[M,K] * B[N,K]^T ----------------
// A bf16 (optionally row-gathered by tok_list), B fp32 (converted to bf16 in staging).
// mode 0: store bf16 C at Cb + e*c_expert_stride, ld=ldc
// mode 1: atomicAdd(out[tok[row]*HDIM + col], val * w_list[row])
// mode 2: plain fp32 store out[row*HDIM + col] = val
#define BM 128
#define BN 128
#define BK 64
#define LDSP (BK + 8)

__launch_bounds__(256, 2)
__global__ void gemm_bt_kernel(
    const unsigned short* __restrict__ Abase, int a_row_stride, long a_expert_stride,
    int gather_a, const int* __restrict__ tok_list,
    const float* __restrict__ Bbase, long b_expert_stride,
    int K, const int* __restrict__ counts, int fixed_rows,
    int mode,
    unsigned short* __restrict__ Cb, long c_expert_stride, int ldc,
    float* __restrict__ outf, const float* __restrict__ w_list)
{
  const int e = blockIdx.z;
  int n_rows = counts ? (counts[e] < CAP ? counts[e] : CAP) : fixed_rows;
  const int m0 = blockIdx.y * BM;
  if (m0 >= n_rows) return;
  const int n0 = blockIdx.x * BN;

  __shared__ unsigned short As[BM * LDSP];
  __shared__ unsigned short Bs[BN * LDSP];

  const int tid = threadIdx.x;
  const int lane = tid & 63;
  const int wv = tid >> 6;
  const int wm = (wv >> 1) * 64;
  const int wn = (wv & 1) * 64;

  const int* tl = tok_list ? (tok_list + e * CAP) : nullptr;
  const unsigned short* Aexp = Abase + (size_t)e * a_expert_stride;
  const float* Bexp = Bbase + (size_t)e * b_expert_stride;

  // staging coords: 2 threads per row, 32 elems (cols) each
  const int srow = tid >> 1;
  const int shalf = (tid & 1) * 32;

  int gr = m0 + srow;
  size_t asrc_row;
  if (gather_a) {
    int t = (gr < n_rows) ? tl[gr] : 0;
    if (t < 0 || t >= T_TOK) t = 0;
    asrc_row = (size_t)t * a_row_stride;
  } else {
    int rr = (gr < n_rows) ? gr : 0;
    asrc_row = (size_t)rr * a_row_stride;
  }
  const unsigned short* aptr = Aexp + asrc_row + shalf;
  const float* bptr = Bexp + (size_t)(n0 + srow) * K + shalf;

  f32x4 acc[16];
#pragma unroll
  for (int i = 0; i < 16; ++i) acc[i] = (f32x4){0.f, 0.f, 0.f, 0.f};

  for (int k0 = 0; k0 < K; k0 += BK) {
    uint4 av[4];
#pragma unroll
    for (int i = 0; i < 4; ++i)
      av[i] = *(const uint4*)(aptr + k0 + i * 8);
    float4 blo[4], bhi[4];
#pragma unroll
    for (int i = 0; i < 4; ++i) {
      blo[i] = *(const float4*)(bptr + k0 + i * 8);
      bhi[i] = *(const float4*)(bptr + k0 + i * 8 + 4);
    }
    __syncthreads();
#pragma unroll
    for (int i = 0; i < 4; ++i)
      *(uint4*)&As[srow * LDSP + shalf + i * 8] = av[i];
#pragma unroll
    for (int i = 0; i < 4; ++i) {
      ushort4 p0, p1;
      p0.x = f2b(blo[i].x); p0.y = f2b(blo[i].y); p0.z = f2b(blo[i].z); p0.w = f2b(blo[i].w);
      p1.x = f2b(bhi[i].x); p1.y = f2b(bhi[i].y); p1.z = f2b(bhi[i].z); p1.w = f2b(bhi[i].w);
      *(ushort4*)&Bs[srow * LDSP + shalf + i * 8] = p0;
      *(ushort4*)&Bs[srow * LDSP + shalf + i * 8 + 4] = p1;
    }
    __syncthreads();
#pragma unroll
    for (int ks = 0; ks < BK; ks += 32) {
      bf16x8 af[4], bfr[4];
#pragma unroll
      for (int mt = 0; mt < 4; ++mt)
        af[mt] = *(const bf16x8*)&As[(wm + mt * 16 + (lane & 15)) * LDSP + ks + (lane >> 4) * 8];
#pragma unroll
      for (int nt = 0; nt < 4; ++nt)
        bfr[nt] = *(const bf16x8*)&Bs[(wn + nt * 16 + (lane & 15)) * LDSP + ks + (lane >> 4) * 8];
#pragma unroll
      for (int mt = 0; mt < 4; ++mt)
#pragma unroll
        for (int nt = 0; nt < 4; ++nt)
          acc[mt * 4 + nt] = __builtin_amdgcn_mfma_f32_16x16x32_bf16(af[mt], bfr[nt], acc[mt * 4 + nt], 0, 0, 0);
    }
  }

  // epilogue: C row = m0+wm+mt*16+(lane>>4)*4+r, col = n0+wn+nt*16+(lane&15)
  if (mode == 0) {
    unsigned short* Ce = Cb + (size_t)e * c_expert_stride;
#pragma unroll
    for (int mt = 0; mt < 4; ++mt) {
#pragma unroll
      for (int r = 0; r < 4; ++r) {
        int gm = m0 + wm + mt * 16 + (lane >> 4) * 4 + r;
        if (gm < n_rows) {
#pragma unroll
          for (int nt = 0; nt < 4; ++nt) {
            int gn = n0 + wn + nt * 16 + (lane & 15);
            Ce[(size_t)gm * ldc + gn] = f2b(acc[mt * 4 + nt][r]);
          }
        }
      }
    }
  } else if (mode == 1) {
#pragma unroll
    for (int mt = 0; mt < 4; ++mt) {
#pragma unroll
      for (int r = 0; r < 4; ++r) {
        int gm = m0 + wm + mt * 16 + (lane >> 4) * 4 + r;
        if (gm < n_rows) {
          int t = tl[gm];
          if (t >= 0 && t < T_TOK) {
            float w = w_list[e * CAP + gm];
#pragma unroll
            for (int nt = 0; nt < 4; ++nt) {
              int gn = n0 + wn + nt * 16 + (lane & 15);
              atomicAdd(outf + (size_t)t * HDIM + gn, acc[mt * 4 + nt][r] * w);
            }
          }
        }
      }
    }
  } else {
#pragma unroll
    for (int mt = 0; mt < 4; ++mt) {
#pragma unroll
      for (int r = 0; r < 4; ++r) {
        int gm = m0 + wm + mt * 16 + (lane >> 4) * 4 + r;
#pragma unroll
        for (int nt = 0; nt < 4; ++nt) {
          int gn = n0 + wn + nt * 16 + (lane & 15);
          outf[(size_t)gm * HDIM + gn] = acc[mt * 4 + nt][r];
        }
      }
    }
  }
}

extern "C" void kernel_launch(void* const* d_in, const int* in_sizes, int n_in,
                              void* d_out, int out_size, void* d_ws, size_t ws_size,
                              hipStream_t stream) {
  const float* x      = (const float*)d_in[0];
  const float* gate_w = (const float*)d_in[1];
  const float* bias   = (const float*)d_in[2];
  const float* w_gate = (const float*)d_in[3];
  const float* w_up   = (const float*)d_in[4];
  const float* w_down = (const float*)d_in[5];
  const float* sg     = (const float*)d_in[6];
  const float* su     = (const float*)d_in[7];
  const float* sd     = (const float*)d_in[8];
  float* out = (float*)d_out;

  char* ws = (char*)d_ws;
  unsigned short* xb16 = (unsigned short*)ws;                       // 8 MB
  unsigned short* Gbuf = (unsigned short*)(ws + (8u << 20));        // 48 MB
  unsigned short* Ubuf = Gbuf + (size_t)NEXP * CAP * IDIM;          // 48 MB
  char* tail = (char*)(Ubuf + (size_t)NEXP * CAP * IDIM);
  int* counts = (int*)tail;
  int* tok_list = counts + 64;
  float* w_list = (float*)(tok_list + NEXP * CAP);

  // 1. setup
  zero32_kernel<<<1, 64, 0, stream>>>(counts);
  cvt_x_kernel<<<(T_TOK * HDIM) / (256 * 4), 256, 0, stream>>>(x, xb16);
  router_kernel<<<T_TOK / 4, 256, 0, stream>>>(x, gate_w, bias, counts, tok_list, w_list);

  // 2. shared expert (writes out with plain stores; routed adds after)
  gemm_bt_kernel<<<dim3(IDIM / BN, T_TOK / BM, 1), 256, 0, stream>>>(
      xb16, HDIM, 0, 0, nullptr, sg, 0, HDIM, nullptr, T_TOK,
      0, Gbuf, 0, IDIM, nullptr, nullptr);
  gemm_bt_kernel<<<dim3(IDIM / BN, T_TOK / BM, 1), 256, 0, stream>>>(
      xb16, HDIM, 0, 0, nullptr, su, 0, HDIM, nullptr, T_TOK,
      0, Ubuf, 0, IDIM, nullptr, nullptr);
  silu_mul_kernel<<<(T_TOK * IDIM / 4) / 256, 256, 0, stream>>>(Gbuf, Ubuf, Gbuf, 1, (long)T_TOK * IDIM / 4);
  gemm_bt_kernel<<<dim3(HDIM / BN, T_TOK / BM, 1), 256, 0, stream>>>(
      Gbuf, IDIM, 0, 0, nullptr, sd, 0, IDIM, nullptr, T_TOK,
      2, nullptr, 0, 0, out, nullptr);

  // 3. routed experts
  gemm_bt_kernel<<<dim3(IDIM / BN, CAP / BM, NEXP), 256, 0, stream>>>(
      xb16, HDIM, 0, 1, tok_list, w_gate, (long)IDIM * HDIM, HDIM, counts, 0,
      0, Gbuf, (long)CAP * IDIM, IDIM, nullptr, nullptr);
  gemm_bt_kernel<<<dim3(IDIM / BN, CAP / BM, NEXP), 256, 0, stream>>>(
      xb16, HDIM, 0, 1, tok_list, w_up, (long)IDIM * HDIM, HDIM, counts, 0,
      0, Ubuf, (long)CAP * IDIM, IDIM, nullptr, nullptr);
  silu_mul_kernel<<<((long)NEXP * CAP * IDIM / 4) / 256, 256, 0, stream>>>(
      Gbuf, Ubuf, Gbuf, 0, (long)NEXP * CAP * IDIM / 4);
  gemm_bt_kernel<<<dim3(HDIM / BN, CAP / BM, NEXP), 256, 0, stream>>>(
      Gbuf, IDIM, (long)CAP * IDIM, 0, tok_list, w_down, (long)HDIM * IDIM, IDIM, counts, 0,
      1, nullptr, 0, 0, out, w_list);
}